// Round 1
// baseline (1459.951 us; speedup 1.0000x reference)
//
#include <hip/hip_runtime.h>
#include <math.h>

// Problem constants
#define B_   32
#define H_   512
#define W_   512
#define C_   3
#define M_   96          // B_*C_
#define NW_  263         // floor((512+15)/2)
#define NH_  263
#define DETPER 69169     // 263*263
#define DETTOT 207507    // 3*DETPER
#define KRANK  103753u   // (DETTOT-1)/2, 0-based median rank
#define CAP_   49152     // candidate capacity per image (~3x expected)

// db8 reconstruction filters (pre-derived; dec filters are reversed versions,
// and the reference's conv reduces to: ca[j] = sum_k xe[2j+k]*rec_lo[k])
__device__ __constant__ float RLO[16] = {
    0.05441584224308161f,  0.3128715909144659f,   0.6756307362980128f,
    0.5853546836548691f,  -0.015829105256023893f, -0.2840155429624281f,
    0.00047248457399797254f, 0.128747426620186f,  -0.01736930100202211f,
   -0.04408825393106472f,  0.013981027917015516f,  0.008746094047015655f,
   -0.00487035299301066f, -0.0003917403729959771f, 0.0006754494059985568f,
   -0.00011747678400228192f};
__device__ __constant__ float RHI[16] = {
   -0.00011747678400228192f, -0.0006754494059985568f, -0.0003917403729959771f,
    0.00487035299301066f,     0.008746094047015655f,  -0.013981027917015516f,
   -0.04408825393106472f,     0.01736930100202211f,    0.128747426620186f,
   -0.00047248457399797254f, -0.2840155429624281f,     0.015829105256023893f,
    0.5853546836548691f,     -0.6756307362980128f,     0.3128715909144659f,
   -0.05441584224308161f};

// Map padded index p (pad: sym 15 left then drop-first => 14 eff, 15 right) to source idx
__device__ __forceinline__ int symmap(int p, int N) {
    int q = p - 14;
    if (q < 0)  return -q - 1;
    if (q >= N) return 2 * N - 1 - q;
    return q;
}

__device__ __forceinline__ float softthr(float v, float thr) {
    float a = fabsf(v) - thr;
    return a > 0.f ? copysignf(a, v) : 0.f;
}

// ---------------- Stage A: row DWT (along W), all 3 channels per block ----------------
__global__ __launch_bounds__(256) void k_rowdwt(const float* __restrict__ x,
                                                float* __restrict__ lo,
                                                float* __restrict__ hi) {
    __shared__ float row[W_ * C_];
    const int hrow = blockIdx.x, b = blockIdx.y, tid = threadIdx.x;
    const float* src = x + (size_t)(b * H_ + hrow) * (W_ * C_);
    for (int i = tid; i < W_ * C_; i += 256) row[i] = src[i];
    __syncthreads();
    for (int task = tid; task < C_ * NW_; task += 256) {
        int j = task % NW_, c = task / NW_;
        float al = 0.f, ah = 0.f;
#pragma unroll
        for (int k = 0; k < 16; ++k) {
            int w = symmap(2 * j + k, W_);
            float v = row[w * C_ + c];
            al = fmaf(v, RLO[k], al);
            ah = fmaf(v, RHI[k], ah);
        }
        size_t o = ((size_t)((b * C_ + c) * H_ + hrow)) * NW_ + j;
        lo[o] = al;
        hi[o] = ah;
    }
}

// ---------------- Stage B: column DWT (along H); lanes on jw => coalesced ----------------
__global__ __launch_bounds__(256) void k_coldwt(const float* __restrict__ lo,
                                                const float* __restrict__ hi,
                                                float* __restrict__ ll, float* __restrict__ lh,
                                                float* __restrict__ hl, float* __restrict__ hh) {
    const int tx = threadIdx.x & 63, ty = threadIdx.x >> 6;
    const int jw = blockIdx.x * 64 + tx;
    const int jh = blockIdx.y * 4 + ty;
    const int m = blockIdx.z;
    if (jw >= NW_ || jh >= NH_) return;
    const float* pl = lo + (size_t)m * H_ * NW_;
    const float* ph = hi + (size_t)m * H_ * NW_;
    float a0 = 0.f, a1 = 0.f, a2 = 0.f, a3 = 0.f;
#pragma unroll
    for (int k = 0; k < 16; ++k) {
        int h = symmap(2 * jh + k, H_);
        float vl = pl[(size_t)h * NW_ + jw];
        float vh = ph[(size_t)h * NW_ + jw];
        a0 = fmaf(vl, RLO[k], a0);
        a1 = fmaf(vl, RHI[k], a1);
        a2 = fmaf(vh, RLO[k], a2);
        a3 = fmaf(vh, RHI[k], a3);
    }
    // stored as [m][jh][jw] (jw contiguous)
    size_t o = ((size_t)m * NH_ + jh) * NW_ + jw;
    ll[o] = a0; lh[o] = a1; hl[o] = a2; hh[o] = a3;
}

// ---------------- Median stage: pass 1 histogram of top 11 bits of |v| ----------------
__global__ __launch_bounds__(256) void k_hist1(const float* __restrict__ lh,
                                               const float* __restrict__ hl,
                                               const float* __restrict__ hh,
                                               unsigned* __restrict__ hist) {
    __shared__ unsigned h[2048];
    const int tid = threadIdx.x, m = blockIdx.x;
    for (int i = tid; i < 2048; i += 256) h[i] = 0u;
    __syncthreads();
    const int stride = gridDim.y * 256;
    for (int i = blockIdx.y * 256 + tid; i < DETTOT; i += stride) {
        const float* p; int ii;
        if (i < DETPER)          { p = lh; ii = i; }
        else if (i < 2 * DETPER) { p = hl; ii = i - DETPER; }
        else                     { p = hh; ii = i - 2 * DETPER; }
        unsigned u = __float_as_uint(fabsf(p[(size_t)m * DETPER + ii]));
        atomicAdd(&h[u >> 21], 1u);
    }
    __syncthreads();
    for (int i = tid; i < 2048; i += 256)
        if (h[i]) atomicAdd(&hist[m * 2048 + i], h[i]);
}

// Cooperative select: find bin of LDS histogram (nb multiple of 256) containing `rank`
__device__ int histSelect(unsigned* hist, int nb, unsigned rank, unsigned* rem) {
    __shared__ unsigned ps[256];
    __shared__ int s_bin;
    __shared__ unsigned s_rem;
    const int tid = threadIdx.x;
    const int per = nb >> 8;
    unsigned s = 0;
    for (int i = 0; i < per; ++i) s += hist[tid * per + i];
    ps[tid] = s;
    __syncthreads();
    for (int off = 1; off < 256; off <<= 1) {
        unsigned v = ps[tid];
        unsigned add = (tid >= off) ? ps[tid - off] : 0u;
        __syncthreads();
        ps[tid] = v + add;
        __syncthreads();
    }
    unsigned incl = ps[tid], excl = incl - s;
    if (rank >= excl && rank < incl) {
        unsigned cum = excl;
        for (int i = 0; i < per; ++i) {
            unsigned c = hist[tid * per + i];
            if (cum + c > rank) { s_bin = tid * per + i; s_rem = rank - cum; break; }
            cum += c;
        }
    }
    __syncthreads();
    int rbin = s_bin;
    unsigned rr = s_rem;
    __syncthreads();   // protect shared reuse across calls
    *rem = rr;
    return rbin;
}

__global__ __launch_bounds__(256) void k_sel1(const unsigned* __restrict__ hist,
                                              int* __restrict__ selBin,
                                              unsigned* __restrict__ rankInBin) {
    __shared__ unsigned h[2048];
    const int m = blockIdx.x, tid = threadIdx.x;
    for (int i = tid; i < 2048; i += 256) h[i] = hist[m * 2048 + i];
    __syncthreads();
    unsigned rem;
    int bin = histSelect(h, 2048, KRANK, &rem);
    if (tid == 0) { selBin[m] = bin; rankInBin[m] = rem; }
}

// Pass 2: extract candidates in selected bin (wave-aggregated atomics)
__global__ __launch_bounds__(256) void k_extract(const float* __restrict__ lh,
                                                 const float* __restrict__ hl,
                                                 const float* __restrict__ hh,
                                                 const int* __restrict__ selBin,
                                                 unsigned* __restrict__ cand,
                                                 unsigned* __restrict__ candCount) {
    const int tid = threadIdx.x, m = blockIdx.x;
    const unsigned target = (unsigned)selBin[m];
    const int lane = tid & 63;
    const int stride = gridDim.y * 256;
    for (int i0 = blockIdx.y * 256; i0 < DETTOT; i0 += stride) {
        int i = i0 + tid;
        bool match = false; unsigned u = 0u;
        if (i < DETTOT) {
            const float* p; int ii;
            if (i < DETPER)          { p = lh; ii = i; }
            else if (i < 2 * DETPER) { p = hl; ii = i - DETPER; }
            else                     { p = hh; ii = i - 2 * DETPER; }
            u = __float_as_uint(fabsf(p[(size_t)m * DETPER + ii]));
            match = (u >> 21) == target;
        }
        unsigned long long mb = __ballot(match);
        if (mb == 0ull) continue;
        int leader = __ffsll((unsigned long long)mb) - 1;
        unsigned base = 0u;
        if (lane == leader) base = atomicAdd(&candCount[m], (unsigned)__popcll(mb));
        base = (unsigned)__shfl((int)base, leader, 64);
        if (match) {
            unsigned pos = base + (unsigned)__popcll(mb & ((1ull << lane) - 1ull));
            if (pos < CAP_) cand[(size_t)m * CAP_ + pos] = u;
        }
    }
}

// Pass 3: per-image final radix select on remaining 21 bits
__global__ __launch_bounds__(256) void k_final(const unsigned* __restrict__ cand,
                                               const unsigned* __restrict__ candCount,
                                               const int* __restrict__ selBin,
                                               const unsigned* __restrict__ rankInBin,
                                               float* __restrict__ tval) {
    __shared__ unsigned h[2048];
    const int m = blockIdx.x, tid = threadIdx.x;
    unsigned n = candCount[m]; if (n > CAP_) n = CAP_;
    const unsigned rank = rankInBin[m];
    const unsigned* cp = cand + (size_t)m * CAP_;
    for (int i = tid; i < 2048; i += 256) h[i] = 0u;
    __syncthreads();
    for (unsigned i = tid; i < n; i += 256) atomicAdd(&h[(cp[i] >> 10) & 0x7FFu], 1u);
    __syncthreads();
    unsigned rem2;
    int bin2 = histSelect(h, 2048, rank, &rem2);
    __syncthreads();
    for (int i = tid; i < 1024; i += 256) h[i] = 0u;
    __syncthreads();
    for (unsigned i = tid; i < n; i += 256) {
        unsigned u = cp[i];
        if (((u >> 10) & 0x7FFu) == (unsigned)bin2) atomicAdd(&h[u & 0x3FFu], 1u);
    }
    __syncthreads();
    unsigned rem3;
    int low = histSelect(h, 1024, rem2, &rem3);
    if (tid == 0) {
        unsigned bits = ((unsigned)selBin[m] << 21) | ((unsigned)bin2 << 10) | (unsigned)low;
        double med = (double)__uint_as_float(bits);
        // t = median/0.6745 * sqrt(2*ln(512*512))
        tval[m] = (float)(med / 0.6745 * 4.995327667046959);
    }
}

// ---------------- Stage G: soft-threshold + column IDWT ----------------
// y[2s+r] = sum_{a=0..7} ca[s+7-a]*RLO[2a+r] + cd[s+7-a]*RHI[2a+r]; indices always in range
__global__ __launch_bounds__(256) void k_colidwt(const float* __restrict__ ll,
                                                 const float* __restrict__ lh,
                                                 const float* __restrict__ hl,
                                                 const float* __restrict__ hh,
                                                 const float* __restrict__ tval,
                                                 float* __restrict__ rl,
                                                 float* __restrict__ rh) {
    const int tx = threadIdx.x & 63, ty = threadIdx.x >> 6;
    const int jw = blockIdx.x * 64 + tx;
    const int t = blockIdx.y * 4 + ty;
    const int m = blockIdx.z;
    if (jw >= NW_) return;
    const float thr = tval[m];
    const int s = t >> 1, r = t & 1;
    float aL = 0.f, aH = 0.f;
    const size_t mb = (size_t)m * NH_ * NW_;
#pragma unroll
    for (int a = 0; a < 8; ++a) {
        int jh = s + 7 - a;
        size_t o = mb + (size_t)jh * NW_ + jw;
        float wl = RLO[2 * a + r], wh = RHI[2 * a + r];
        float vll = ll[o];
        float vlh = softthr(lh[o], thr);
        float vhl = softthr(hl[o], thr);
        float vhh = softthr(hh[o], thr);
        aL = fmaf(vll, wl, fmaf(vlh, wh, aL));
        aH = fmaf(vhl, wl, fmaf(vhh, wh, aH));
    }
    size_t o = ((size_t)m * H_ + t) * NW_ + jw;
    rl[o] = aL;
    rh[o] = aH;
}

// ---------------- Stage H: row IDWT + NHWC output write ----------------
__global__ __launch_bounds__(256) void k_rowidwt(const float* __restrict__ rl,
                                                 const float* __restrict__ rh,
                                                 float* __restrict__ out) {
    __shared__ float rlr[C_ * NW_], rhr[C_ * NW_];
    const int hrow = blockIdx.x, b = blockIdx.y, tid = threadIdx.x;
    for (int i = tid; i < C_ * NW_; i += 256) {
        int c = i / NW_, j = i - c * NW_;
        size_t o = ((size_t)((b * C_ + c) * H_) + hrow) * NW_ + j;
        rlr[i] = rl[o];
        rhr[i] = rh[o];
    }
    __syncthreads();
    float* dst = out + (size_t)(b * H_ + hrow) * (W_ * C_);
    for (int task = tid; task < W_ * C_; task += 256) {
        int w = task / C_, c = task - C_ * (task / C_);
        int s = w >> 1, r = w & 1;
        float acc = 0.f;
#pragma unroll
        for (int a = 0; a < 8; ++a) {
            int j = s + 7 - a;
            acc = fmaf(rlr[c * NW_ + j], RLO[2 * a + r],
                       fmaf(rhr[c * NW_ + j], RHI[2 * a + r], acc));
        }
        dst[task] = acc;
    }
}

extern "C" void kernel_launch(void* const* d_in, const int* in_sizes, int n_in,
                              void* d_out, int out_size, void* d_ws, size_t ws_size,
                              hipStream_t stream) {
    const float* x = (const float*)d_in[0];
    float* out = (float*)d_out;

    char* ws = (char*)d_ws;
    const size_t LOSZ = (size_t)M_ * H_ * NW_;   // 12,926,976 floats
    const size_t SBSZ = (size_t)M_ * NH_ * NW_;  //  6,640,224 floats
    float* lo = (float*)ws; ws += LOSZ * 4;
    float* hi = (float*)ws; ws += LOSZ * 4;
    float* ll = (float*)ws; ws += SBSZ * 4;
    float* lh = (float*)ws; ws += SBSZ * 4;
    float* hl = (float*)ws; ws += SBSZ * 4;
    float* hh = (float*)ws; ws += SBSZ * 4;
    unsigned* hist1     = (unsigned*)ws; ws += (size_t)M_ * 2048 * 4;
    int*      selBin    = (int*)ws;      ws += M_ * 4;
    unsigned* rankInBin = (unsigned*)ws; ws += M_ * 4;
    unsigned* candCount = (unsigned*)ws; ws += M_ * 4;
    float*    tval      = (float*)ws;    ws += M_ * 4;
    // cand aliases lo (dead between stage B and stage G); rl/rh alias lo/hi after median.
    unsigned* cand = (unsigned*)lo;      // needs 96*49152*4 = 18.9 MB < 51.7 MB
    float* rl = lo;
    float* rh = hi;

    hipMemsetAsync(hist1, 0, (size_t)M_ * 2048 * 4, stream);
    hipMemsetAsync(candCount, 0, M_ * 4, stream);

    k_rowdwt <<<dim3(H_, B_),        256, 0, stream>>>(x, lo, hi);
    k_coldwt <<<dim3(5, 66, M_),     256, 0, stream>>>(lo, hi, ll, lh, hl, hh);
    k_hist1  <<<dim3(M_, 16),        256, 0, stream>>>(lh, hl, hh, hist1);
    k_sel1   <<<dim3(M_),            256, 0, stream>>>(hist1, selBin, rankInBin);
    k_extract<<<dim3(M_, 16),        256, 0, stream>>>(lh, hl, hh, selBin, cand, candCount);
    k_final  <<<dim3(M_),            256, 0, stream>>>(cand, candCount, selBin, rankInBin, tval);
    k_colidwt<<<dim3(5, 128, M_),    256, 0, stream>>>(ll, lh, hl, hh, tval, rl, rh);
    k_rowidwt<<<dim3(H_, B_),        256, 0, stream>>>(rl, rh, out);
}

// Round 2
// 514.398 us; speedup vs baseline: 2.8382x; 2.8382x over previous
//
#include <hip/hip_runtime.h>
#include <math.h>

// Problem constants
#define B_   32
#define H_   512
#define W_   512
#define C_   3
#define M_   96          // B_*C_
#define NW_  263         // floor((512+15)/2)
#define NH_  263
#define DETPER 69169     // 263*263
#define DETTOT 207507    // 3*DETPER
#define KRANK  103753u   // (DETTOT-1)/2, 0-based median rank

// db8 reconstruction filters (pre-derived; dec filters are reversed versions,
// and the reference's conv reduces to: ca[j] = sum_k xe[2j+k]*rec_lo[k])
__device__ __constant__ float RLO[16] = {
    0.05441584224308161f,  0.3128715909144659f,   0.6756307362980128f,
    0.5853546836548691f,  -0.015829105256023893f, -0.2840155429624281f,
    0.00047248457399797254f, 0.128747426620186f,  -0.01736930100202211f,
   -0.04408825393106472f,  0.013981027917015516f,  0.008746094047015655f,
   -0.00487035299301066f, -0.0003917403729959771f, 0.0006754494059985568f,
   -0.00011747678400228192f};
__device__ __constant__ float RHI[16] = {
   -0.00011747678400228192f, -0.0006754494059985568f, -0.0003917403729959771f,
    0.00487035299301066f,     0.008746094047015655f,  -0.013981027917015516f,
   -0.04408825393106472f,     0.01736930100202211f,    0.128747426620186f,
   -0.00047248457399797254f, -0.2840155429624281f,     0.015829105256023893f,
    0.5853546836548691f,     -0.6756307362980128f,     0.3128715909144659f,
   -0.05441584224308161f};

// Map padded index p (pad: sym 15 left then drop-first => 14 eff, 15 right) to source idx
__device__ __forceinline__ int symmap(int p, int N) {
    int q = p - 14;
    if (q < 0)  return -q - 1;
    if (q >= N) return 2 * N - 1 - q;
    return q;
}

__device__ __forceinline__ float softthr(float v, float thr) {
    float a = fabsf(v) - thr;
    return a > 0.f ? copysignf(a, v) : 0.f;
}

// Fetch |detail| bit pattern for flat index i in [0, DETTOT) of image m
__device__ __forceinline__ unsigned detbits(const float* lh, const float* hl,
                                            const float* hh, int m, int i) {
    const float* p; int ii;
    if (i < DETPER)          { p = lh; ii = i; }
    else if (i < 2 * DETPER) { p = hl; ii = i - DETPER; }
    else                     { p = hh; ii = i - 2 * DETPER; }
    return __float_as_uint(fabsf(p[(size_t)m * DETPER + ii]));
}

// ---------------- Stage A: row DWT (along W), all 3 channels per block ----------------
__global__ __launch_bounds__(256) void k_rowdwt(const float* __restrict__ x,
                                                float* __restrict__ lo,
                                                float* __restrict__ hi) {
    __shared__ float row[W_ * C_];
    const int hrow = blockIdx.x, b = blockIdx.y, tid = threadIdx.x;
    const float* src = x + (size_t)(b * H_ + hrow) * (W_ * C_);
    for (int i = tid; i < W_ * C_; i += 256) row[i] = src[i];
    __syncthreads();
    for (int task = tid; task < C_ * NW_; task += 256) {
        int j = task % NW_, c = task / NW_;
        float al = 0.f, ah = 0.f;
#pragma unroll
        for (int k = 0; k < 16; ++k) {
            int w = symmap(2 * j + k, W_);
            float v = row[w * C_ + c];
            al = fmaf(v, RLO[k], al);
            ah = fmaf(v, RHI[k], ah);
        }
        size_t o = ((size_t)((b * C_ + c) * H_ + hrow)) * NW_ + j;
        lo[o] = al;
        hi[o] = ah;
    }
}

// ---------------- Stage B: column DWT (along H); lanes on jw => coalesced ----------------
__global__ __launch_bounds__(256) void k_coldwt(const float* __restrict__ lo,
                                                const float* __restrict__ hi,
                                                float* __restrict__ ll, float* __restrict__ lh,
                                                float* __restrict__ hl, float* __restrict__ hh) {
    const int tx = threadIdx.x & 63, ty = threadIdx.x >> 6;
    const int jw = blockIdx.x * 64 + tx;
    const int jh = blockIdx.y * 4 + ty;
    const int m = blockIdx.z;
    if (jw >= NW_ || jh >= NH_) return;
    const float* pl = lo + (size_t)m * H_ * NW_;
    const float* ph = hi + (size_t)m * H_ * NW_;
    float a0 = 0.f, a1 = 0.f, a2 = 0.f, a3 = 0.f;
#pragma unroll
    for (int k = 0; k < 16; ++k) {
        int h = symmap(2 * jh + k, H_);
        float vl = pl[(size_t)h * NW_ + jw];
        float vh = ph[(size_t)h * NW_ + jw];
        a0 = fmaf(vl, RLO[k], a0);
        a1 = fmaf(vl, RHI[k], a1);
        a2 = fmaf(vh, RLO[k], a2);
        a3 = fmaf(vh, RHI[k], a3);
    }
    // stored as [m][jh][jw] (jw contiguous)
    size_t o = ((size_t)m * NH_ + jh) * NW_ + jw;
    ll[o] = a0; lh[o] = a1; hl[o] = a2; hh[o] = a3;
}

// ---------------- Median: 3-pass radix histogram refinement (no extraction) -----------
// Pass 1: histogram of bits [31:21] of |v|
__global__ __launch_bounds__(256) void k_hist1(const float* __restrict__ lh,
                                               const float* __restrict__ hl,
                                               const float* __restrict__ hh,
                                               unsigned* __restrict__ hist) {
    __shared__ unsigned h[2048];
    const int tid = threadIdx.x, m = blockIdx.x;
    for (int i = tid; i < 2048; i += 256) h[i] = 0u;
    __syncthreads();
    const int stride = gridDim.y * 256;
    for (int i = blockIdx.y * 256 + tid; i < DETTOT; i += stride) {
        unsigned u = detbits(lh, hl, hh, m, i);
        atomicAdd(&h[u >> 21], 1u);
    }
    __syncthreads();
    for (int i = tid; i < 2048; i += 256)
        if (h[i]) atomicAdd(&hist[m * 2048 + i], h[i]);
}

// Pass 2: among elements with top-11 bits == bin1, histogram bits [20:10]
__global__ __launch_bounds__(256) void k_hist2(const float* __restrict__ lh,
                                               const float* __restrict__ hl,
                                               const float* __restrict__ hh,
                                               const int* __restrict__ selBin1,
                                               unsigned* __restrict__ hist) {
    __shared__ unsigned h[2048];
    const int tid = threadIdx.x, m = blockIdx.x;
    const unsigned target = (unsigned)selBin1[m];
    for (int i = tid; i < 2048; i += 256) h[i] = 0u;
    __syncthreads();
    const int stride = gridDim.y * 256;
    for (int i = blockIdx.y * 256 + tid; i < DETTOT; i += stride) {
        unsigned u = detbits(lh, hl, hh, m, i);
        if ((u >> 21) == target) atomicAdd(&h[(u >> 10) & 0x7FFu], 1u);
    }
    __syncthreads();
    for (int i = tid; i < 2048; i += 256)
        if (h[i]) atomicAdd(&hist[m * 2048 + i], h[i]);
}

// Pass 3: among elements with top-22 bits == (bin1<<11)|bin2, histogram bits [9:0]
__global__ __launch_bounds__(256) void k_hist3(const float* __restrict__ lh,
                                               const float* __restrict__ hl,
                                               const float* __restrict__ hh,
                                               const int* __restrict__ selBin1,
                                               const int* __restrict__ selBin2,
                                               unsigned* __restrict__ hist) {
    __shared__ unsigned h[1024];
    const int tid = threadIdx.x, m = blockIdx.x;
    const unsigned target = ((unsigned)selBin1[m] << 11) | (unsigned)selBin2[m];
    for (int i = tid; i < 1024; i += 256) h[i] = 0u;
    __syncthreads();
    const int stride = gridDim.y * 256;
    for (int i = blockIdx.y * 256 + tid; i < DETTOT; i += stride) {
        unsigned u = detbits(lh, hl, hh, m, i);
        if ((u >> 10) == target) atomicAdd(&h[u & 0x3FFu], 1u);
    }
    __syncthreads();
    for (int i = tid; i < 1024; i += 256)
        if (h[i]) atomicAdd(&hist[m * 1024 + i], h[i]);
}

// Cooperative select: find bin of LDS histogram (nb multiple of 256) containing `rank`
__device__ int histSelect(unsigned* hist, int nb, unsigned rank, unsigned* rem) {
    __shared__ unsigned ps[256];
    __shared__ int s_bin;
    __shared__ unsigned s_rem;
    const int tid = threadIdx.x;
    const int per = nb >> 8;
    unsigned s = 0;
    for (int i = 0; i < per; ++i) s += hist[tid * per + i];
    ps[tid] = s;
    __syncthreads();
    for (int off = 1; off < 256; off <<= 1) {
        unsigned v = ps[tid];
        unsigned add = (tid >= off) ? ps[tid - off] : 0u;
        __syncthreads();
        ps[tid] = v + add;
        __syncthreads();
    }
    unsigned incl = ps[tid], excl = incl - s;
    if (rank >= excl && rank < incl) {
        unsigned cum = excl;
        for (int i = 0; i < per; ++i) {
            unsigned c = hist[tid * per + i];
            if (cum + c > rank) { s_bin = tid * per + i; s_rem = rank - cum; break; }
            cum += c;
        }
    }
    __syncthreads();
    int rbin = s_bin;
    unsigned rr = s_rem;
    __syncthreads();   // protect shared reuse across calls
    *rem = rr;
    return rbin;
}

__global__ __launch_bounds__(256) void k_sel2048(const unsigned* __restrict__ hist,
                                                 const unsigned* __restrict__ rankIn, // null => KRANK
                                                 int* __restrict__ selBin,
                                                 unsigned* __restrict__ rankOut) {
    __shared__ unsigned h[2048];
    const int m = blockIdx.x, tid = threadIdx.x;
    for (int i = tid; i < 2048; i += 256) h[i] = hist[m * 2048 + i];
    __syncthreads();
    unsigned rank = rankIn ? rankIn[m] : KRANK;
    unsigned rem;
    int bin = histSelect(h, 2048, rank, &rem);
    if (tid == 0) { selBin[m] = bin; rankOut[m] = rem; }
}

__global__ __launch_bounds__(256) void k_sel3(const unsigned* __restrict__ hist,
                                              const unsigned* __restrict__ rankIn,
                                              const int* __restrict__ selBin1,
                                              const int* __restrict__ selBin2,
                                              float* __restrict__ tval) {
    __shared__ unsigned h[1024];
    const int m = blockIdx.x, tid = threadIdx.x;
    for (int i = tid; i < 1024; i += 256) h[i] = hist[m * 1024 + i];
    __syncthreads();
    unsigned rem;
    int low = histSelect(h, 1024, rankIn[m], &rem);
    if (tid == 0) {
        unsigned bits = ((unsigned)selBin1[m] << 21) | ((unsigned)selBin2[m] << 10) | (unsigned)low;
        double med = (double)__uint_as_float(bits);
        // t = median/0.6745 * sqrt(2*ln(512*512))
        tval[m] = (float)(med / 0.6745 * 4.995327667046959);
    }
}

// ---------------- Stage G: soft-threshold + column IDWT ----------------
// y[2s+r] = sum_{a=0..7} ca[s+7-a]*RLO[2a+r] + cd[s+7-a]*RHI[2a+r]; indices always in range
__global__ __launch_bounds__(256) void k_colidwt(const float* __restrict__ ll,
                                                 const float* __restrict__ lh,
                                                 const float* __restrict__ hl,
                                                 const float* __restrict__ hh,
                                                 const float* __restrict__ tval,
                                                 float* __restrict__ rl,
                                                 float* __restrict__ rh) {
    const int tx = threadIdx.x & 63, ty = threadIdx.x >> 6;
    const int jw = blockIdx.x * 64 + tx;
    const int t = blockIdx.y * 4 + ty;
    const int m = blockIdx.z;
    if (jw >= NW_) return;
    const float thr = tval[m];
    const int s = t >> 1, r = t & 1;
    float aL = 0.f, aH = 0.f;
    const size_t mb = (size_t)m * NH_ * NW_;
#pragma unroll
    for (int a = 0; a < 8; ++a) {
        int jh = s + 7 - a;
        size_t o = mb + (size_t)jh * NW_ + jw;
        float wl = RLO[2 * a + r], wh = RHI[2 * a + r];
        float vll = ll[o];
        float vlh = softthr(lh[o], thr);
        float vhl = softthr(hl[o], thr);
        float vhh = softthr(hh[o], thr);
        aL = fmaf(vll, wl, fmaf(vlh, wh, aL));
        aH = fmaf(vhl, wl, fmaf(vhh, wh, aH));
    }
    size_t o = ((size_t)m * H_ + t) * NW_ + jw;
    rl[o] = aL;
    rh[o] = aH;
}

// ---------------- Stage H: row IDWT + NHWC output write ----------------
__global__ __launch_bounds__(256) void k_rowidwt(const float* __restrict__ rl,
                                                 const float* __restrict__ rh,
                                                 float* __restrict__ out) {
    __shared__ float rlr[C_ * NW_], rhr[C_ * NW_];
    const int hrow = blockIdx.x, b = blockIdx.y, tid = threadIdx.x;
    for (int i = tid; i < C_ * NW_; i += 256) {
        int c = i / NW_, j = i - c * NW_;
        size_t o = ((size_t)((b * C_ + c) * H_) + hrow) * NW_ + j;
        rlr[i] = rl[o];
        rhr[i] = rh[o];
    }
    __syncthreads();
    float* dst = out + (size_t)(b * H_ + hrow) * (W_ * C_);
    for (int task = tid; task < W_ * C_; task += 256) {
        int w = task / C_, c = task - C_ * (task / C_);
        int s = w >> 1, r = w & 1;
        float acc = 0.f;
#pragma unroll
        for (int a = 0; a < 8; ++a) {
            int j = s + 7 - a;
            acc = fmaf(rlr[c * NW_ + j], RLO[2 * a + r],
                       fmaf(rhr[c * NW_ + j], RHI[2 * a + r], acc));
        }
        dst[task] = acc;
    }
}

extern "C" void kernel_launch(void* const* d_in, const int* in_sizes, int n_in,
                              void* d_out, int out_size, void* d_ws, size_t ws_size,
                              hipStream_t stream) {
    const float* x = (const float*)d_in[0];
    float* out = (float*)d_out;

    char* ws = (char*)d_ws;
    const size_t LOSZ = (size_t)M_ * H_ * NW_;   // 12,926,976 floats
    const size_t SBSZ = (size_t)M_ * NH_ * NW_;  //  6,640,224 floats
    float* lo = (float*)ws; ws += LOSZ * 4;
    float* hi = (float*)ws; ws += LOSZ * 4;
    float* ll = (float*)ws; ws += SBSZ * 4;
    float* lh = (float*)ws; ws += SBSZ * 4;
    float* hl = (float*)ws; ws += SBSZ * 4;
    float* hh = (float*)ws; ws += SBSZ * 4;
    // hist1 (2048) + hist2 (2048) + hist3 (1024) per image, contiguous for one memset
    unsigned* hist1 = (unsigned*)ws; ws += (size_t)M_ * 2048 * 4;
    unsigned* hist2 = (unsigned*)ws; ws += (size_t)M_ * 2048 * 4;
    unsigned* hist3 = (unsigned*)ws; ws += (size_t)M_ * 1024 * 4;
    int*      selBin1 = (int*)ws;      ws += M_ * 4;
    int*      selBin2 = (int*)ws;      ws += M_ * 4;
    unsigned* rank1   = (unsigned*)ws; ws += M_ * 4;
    unsigned* rank2   = (unsigned*)ws; ws += M_ * 4;
    float*    tval    = (float*)ws;    ws += M_ * 4;
    // rl/rh alias lo/hi (dead after median stage reads only subbands)
    float* rl = lo;
    float* rh = hi;

    hipMemsetAsync(hist1, 0, (size_t)M_ * (2048 + 2048 + 1024) * 4, stream);

    k_rowdwt <<<dim3(H_, B_),     256, 0, stream>>>(x, lo, hi);
    k_coldwt <<<dim3(5, 66, M_),  256, 0, stream>>>(lo, hi, ll, lh, hl, hh);
    k_hist1  <<<dim3(M_, 16),     256, 0, stream>>>(lh, hl, hh, hist1);
    k_sel2048<<<dim3(M_),         256, 0, stream>>>(hist1, nullptr, selBin1, rank1);
    k_hist2  <<<dim3(M_, 16),     256, 0, stream>>>(lh, hl, hh, selBin1, hist2);
    k_sel2048<<<dim3(M_),         256, 0, stream>>>(hist2, rank1, selBin2, rank2);
    k_hist3  <<<dim3(M_, 16),     256, 0, stream>>>(lh, hl, hh, selBin1, selBin2, hist3);
    k_sel3   <<<dim3(M_),         256, 0, stream>>>(hist3, rank2, selBin1, selBin2, tval);
    k_colidwt<<<dim3(5, 128, M_), 256, 0, stream>>>(ll, lh, hl, hh, tval, rl, rh);
    k_rowidwt<<<dim3(H_, B_),     256, 0, stream>>>(rl, rh, out);
}

// Round 4
// 433.110 us; speedup vs baseline: 3.3709x; 1.1877x over previous
//
#include <hip/hip_runtime.h>
#include <math.h>

// Problem constants
#define B_   32
#define H_   512
#define W_   512
#define C_   3
#define M_   96          // B_*C_
#define NW_  263         // floor((512+15)/2)
#define NH_  263
#define DETPER 69169     // 263*263
#define DETTOT 207507    // 3*DETPER
#define DETSTRIDE 207508 // padded to multiple of 4 for float4 alignment
#define NVEC 51876       // DETTOT/4 (floor); tail = 3 elements
#define KRANK  103753u   // (DETTOT-1)/2, 0-based median rank

// db8 reconstruction filters (pre-derived; dec filters are reversed versions,
// and the reference's conv reduces to: ca[j] = sum_k xe[2j+k]*rec_lo[k])
__device__ __constant__ float RLO[16] = {
    0.05441584224308161f,  0.3128715909144659f,   0.6756307362980128f,
    0.5853546836548691f,  -0.015829105256023893f, -0.2840155429624281f,
    0.00047248457399797254f, 0.128747426620186f,  -0.01736930100202211f,
   -0.04408825393106472f,  0.013981027917015516f,  0.008746094047015655f,
   -0.00487035299301066f, -0.0003917403729959771f, 0.0006754494059985568f,
   -0.00011747678400228192f};
__device__ __constant__ float RHI[16] = {
   -0.00011747678400228192f, -0.0006754494059985568f, -0.0003917403729959771f,
    0.00487035299301066f,     0.008746094047015655f,  -0.013981027917015516f,
   -0.04408825393106472f,     0.01736930100202211f,    0.128747426620186f,
   -0.00047248457399797254f, -0.2840155429624281f,     0.015829105256023893f,
    0.5853546836548691f,     -0.6756307362980128f,     0.3128715909144659f,
   -0.05441584224308161f};

// Symmetric reflection of padded index q into [0, N)
__device__ __forceinline__ int refl(int q, int N) {
    if (q < 0)  return -q - 1;
    if (q >= N) return 2 * N - 1 - q;
    return q;
}

__device__ __forceinline__ float softthr(float v, float thr) {
    float a = fabsf(v) - thr;
    return a > 0.f ? copysignf(a, v) : 0.f;
}

// -------- zero-init for histogram region (no hipMemsetAsync in capture) --------
__global__ __launch_bounds__(256) void k_zero(unsigned* __restrict__ p, int n) {
    int i = blockIdx.x * 256 + threadIdx.x;
    if (i < n) p[i] = 0u;
}

// ---------------- Fused forward: row DWT + column DWT ----------------
// One block per (m, 64-jw tile, 16-jh tile). Stages 46 x-rows x 142 x-cols of one
// channel (26.5 KB), row-DWTs them to 46x64 lo/hi (23.5 KB), col-DWTs to ll/det.
__global__ __launch_bounds__(256) void k_fwd(const float* __restrict__ x,
                                             float* __restrict__ ll,
                                             float* __restrict__ det) {
    __shared__ float sX[46 * 144];               // 142 cols padded to 144
    __shared__ float sLO[46 * 64], sHI[46 * 64];
    const int m   = blockIdx.x;                  // channels adjacent in dispatch
    const int jw0 = blockIdx.y * 64;             // 5 tiles
    const int jh0 = blockIdx.z * 16;             // 17 tiles
    const int b = m / 3, c = m - 3 * (m / 3);
    const int tid = threadIdx.x;
    const int prow0 = 2 * jh0 - 14, pcol0 = 2 * jw0 - 14;
    // stage x tile (channel c), symmetric-reflected at borders
    for (int l = tid; l < 46 * 142; l += 256) {
        int rr = l / 142, cl = l - rr * 142;
        int h = refl(prow0 + rr, H_);
        int w = refl(pcol0 + cl, W_);
        sX[rr * 144 + cl] = x[((size_t)(b * H_ + h) * W_ + w) * C_ + c];
    }
    __syncthreads();
    // row DWT: 46 padded-rows x 64 j-cols
    for (int l = tid; l < 46 * 64; l += 256) {
        int rr = l >> 6, j = l & 63;
        const float* px = &sX[rr * 144 + 2 * j];
        float al = 0.f, ah = 0.f;
#pragma unroll
        for (int k = 0; k < 16; ++k) {
            al = fmaf(px[k], RLO[k], al);
            ah = fmaf(px[k], RHI[k], ah);
        }
        sLO[l] = al;
        sHI[l] = ah;
    }
    __syncthreads();
    // column DWT -> ll, det
    const int tx = tid & 63, ty = tid >> 6;
    const int jw = jw0 + tx;
    if (jw >= NW_) return;
    float* llp = ll + (size_t)m * DETPER;
    float* dp  = det + (size_t)m * DETSTRIDE;
#pragma unroll
    for (int i = 0; i < 4; ++i) {
        int dy = ty + 4 * i;                     // 0..15
        int jh = jh0 + dy;
        if (jh >= NH_) continue;
        int rbase = 2 * dy;
        float a0 = 0.f, a1 = 0.f, a2 = 0.f, a3 = 0.f;
#pragma unroll
        for (int k = 0; k < 16; ++k) {
            float vl = sLO[(rbase + k) * 64 + tx];
            float vh = sHI[(rbase + k) * 64 + tx];
            a0 = fmaf(vl, RLO[k], a0);
            a1 = fmaf(vl, RHI[k], a1);
            a2 = fmaf(vh, RLO[k], a2);
            a3 = fmaf(vh, RHI[k], a3);
        }
        size_t o = (size_t)jh * NW_ + jw;
        llp[o] = a0;                             // LL
        dp[o] = a1;                              // LH
        dp[DETPER + o] = a2;                     // HL
        dp[2 * DETPER + o] = a3;                 // HH
    }
}

// ---------------- Median: 3-pass radix histogram refinement over det ----------
__global__ __launch_bounds__(256) void k_hist1(const float* __restrict__ det,
                                               unsigned* __restrict__ hist) {
    __shared__ unsigned h[2048];
    const int tid = threadIdx.x, m = blockIdx.x;
    for (int i = tid; i < 2048; i += 256) h[i] = 0u;
    __syncthreads();
    const float* dp = det + (size_t)m * DETSTRIDE;
    const float4* dp4 = (const float4*)dp;
    const int stride = gridDim.y * 256;
    for (int v = blockIdx.y * 256 + tid; v < NVEC; v += stride) {
        float4 f = dp4[v];
        atomicAdd(&h[__float_as_uint(fabsf(f.x)) >> 21], 1u);
        atomicAdd(&h[__float_as_uint(fabsf(f.y)) >> 21], 1u);
        atomicAdd(&h[__float_as_uint(fabsf(f.z)) >> 21], 1u);
        atomicAdd(&h[__float_as_uint(fabsf(f.w)) >> 21], 1u);
    }
    if (blockIdx.y == 0 && tid < DETTOT - 4 * NVEC) {
        unsigned u = __float_as_uint(fabsf(dp[4 * NVEC + tid]));
        atomicAdd(&h[u >> 21], 1u);
    }
    __syncthreads();
    for (int i = tid; i < 2048; i += 256)
        if (h[i]) atomicAdd(&hist[m * 2048 + i], h[i]);
}

__global__ __launch_bounds__(256) void k_hist2(const float* __restrict__ det,
                                               const int* __restrict__ selBin1,
                                               unsigned* __restrict__ hist) {
    __shared__ unsigned h[2048];
    const int tid = threadIdx.x, m = blockIdx.x;
    const unsigned target = (unsigned)selBin1[m];
    for (int i = tid; i < 2048; i += 256) h[i] = 0u;
    __syncthreads();
    const float* dp = det + (size_t)m * DETSTRIDE;
    const float4* dp4 = (const float4*)dp;
    const int stride = gridDim.y * 256;
    for (int v = blockIdx.y * 256 + tid; v < NVEC; v += stride) {
        float4 f = dp4[v];
        unsigned a = __float_as_uint(fabsf(f.x));
        unsigned b = __float_as_uint(fabsf(f.y));
        unsigned c = __float_as_uint(fabsf(f.z));
        unsigned d = __float_as_uint(fabsf(f.w));
        if ((a >> 21) == target) atomicAdd(&h[(a >> 10) & 0x7FFu], 1u);
        if ((b >> 21) == target) atomicAdd(&h[(b >> 10) & 0x7FFu], 1u);
        if ((c >> 21) == target) atomicAdd(&h[(c >> 10) & 0x7FFu], 1u);
        if ((d >> 21) == target) atomicAdd(&h[(d >> 10) & 0x7FFu], 1u);
    }
    if (blockIdx.y == 0 && tid < DETTOT - 4 * NVEC) {
        unsigned u = __float_as_uint(fabsf(dp[4 * NVEC + tid]));
        if ((u >> 21) == target) atomicAdd(&h[(u >> 10) & 0x7FFu], 1u);
    }
    __syncthreads();
    for (int i = tid; i < 2048; i += 256)
        if (h[i]) atomicAdd(&hist[m * 2048 + i], h[i]);
}

__global__ __launch_bounds__(256) void k_hist3(const float* __restrict__ det,
                                               const int* __restrict__ selBin1,
                                               const int* __restrict__ selBin2,
                                               unsigned* __restrict__ hist) {
    __shared__ unsigned h[1024];
    const int tid = threadIdx.x, m = blockIdx.x;
    const unsigned target = ((unsigned)selBin1[m] << 11) | (unsigned)selBin2[m];
    for (int i = tid; i < 1024; i += 256) h[i] = 0u;
    __syncthreads();
    const float* dp = det + (size_t)m * DETSTRIDE;
    const float4* dp4 = (const float4*)dp;
    const int stride = gridDim.y * 256;
    for (int v = blockIdx.y * 256 + tid; v < NVEC; v += stride) {
        float4 f = dp4[v];
        unsigned a = __float_as_uint(fabsf(f.x));
        unsigned b = __float_as_uint(fabsf(f.y));
        unsigned c = __float_as_uint(fabsf(f.z));
        unsigned d = __float_as_uint(fabsf(f.w));
        if ((a >> 10) == target) atomicAdd(&h[a & 0x3FFu], 1u);
        if ((b >> 10) == target) atomicAdd(&h[b & 0x3FFu], 1u);
        if ((c >> 10) == target) atomicAdd(&h[c & 0x3FFu], 1u);
        if ((d >> 10) == target) atomicAdd(&h[d & 0x3FFu], 1u);
    }
    if (blockIdx.y == 0 && tid < DETTOT - 4 * NVEC) {
        unsigned u = __float_as_uint(fabsf(dp[4 * NVEC + tid]));
        if ((u >> 10) == target) atomicAdd(&h[u & 0x3FFu], 1u);
    }
    __syncthreads();
    for (int i = tid; i < 1024; i += 256)
        if (h[i]) atomicAdd(&hist[m * 1024 + i], h[i]);
}

// Cooperative select: find bin of LDS histogram (nb multiple of 256) containing `rank`
__device__ int histSelect(unsigned* hist, int nb, unsigned rank, unsigned* rem) {
    __shared__ unsigned ps[256];
    __shared__ int s_bin;
    __shared__ unsigned s_rem;
    const int tid = threadIdx.x;
    if (tid == 0) { s_bin = 0; s_rem = 0; }      // deterministic fallback
    const int per = nb >> 8;
    unsigned s = 0;
    for (int i = 0; i < per; ++i) s += hist[tid * per + i];
    ps[tid] = s;
    __syncthreads();
    for (int off = 1; off < 256; off <<= 1) {
        unsigned v = ps[tid];
        unsigned add = (tid >= off) ? ps[tid - off] : 0u;
        __syncthreads();
        ps[tid] = v + add;
        __syncthreads();
    }
    unsigned incl = ps[tid], excl = incl - s;
    if (rank >= excl && rank < incl) {
        unsigned cum = excl;
        for (int i = 0; i < per; ++i) {
            unsigned c = hist[tid * per + i];
            if (cum + c > rank) { s_bin = tid * per + i; s_rem = rank - cum; break; }
            cum += c;
        }
    }
    __syncthreads();
    int rbin = s_bin;
    unsigned rr = s_rem;
    __syncthreads();   // protect shared reuse across calls
    *rem = rr;
    return rbin;
}

__global__ __launch_bounds__(256) void k_sel2048(const unsigned* __restrict__ hist,
                                                 const unsigned* __restrict__ rankIn, // null => KRANK
                                                 int* __restrict__ selBin,
                                                 unsigned* __restrict__ rankOut) {
    __shared__ unsigned h[2048];
    const int m = blockIdx.x, tid = threadIdx.x;
    for (int i = tid; i < 2048; i += 256) h[i] = hist[m * 2048 + i];
    __syncthreads();
    unsigned rank = rankIn ? rankIn[m] : KRANK;
    unsigned rem;
    int bin = histSelect(h, 2048, rank, &rem);
    if (tid == 0) { selBin[m] = bin; rankOut[m] = rem; }
}

__global__ __launch_bounds__(256) void k_sel3(const unsigned* __restrict__ hist,
                                              const unsigned* __restrict__ rankIn,
                                              const int* __restrict__ selBin1,
                                              const int* __restrict__ selBin2,
                                              float* __restrict__ tval) {
    __shared__ unsigned h[1024];
    const int m = blockIdx.x, tid = threadIdx.x;
    for (int i = tid; i < 1024; i += 256) h[i] = hist[m * 1024 + i];
    __syncthreads();
    unsigned rem;
    int low = histSelect(h, 1024, rankIn[m], &rem);
    if (tid == 0) {
        unsigned bits = ((unsigned)selBin1[m] << 21) | ((unsigned)selBin2[m] << 10) | (unsigned)low;
        double med = (double)__uint_as_float(bits);
        // t = median/0.6745 * sqrt(2*ln(512*512))
        tval[m] = (float)(med / 0.6745 * 4.995327667046959);
    }
}

// ---------------- Fused inverse: soft-threshold + column IDWT + row IDWT ------
// One block per (m, 64-w tile, 32-t tile). Stages 23x39 of 4 subbands (thresholded),
// computes 32x39 rl/rh in LDS, then row-IDWT to a 32x64 output tile (NHWC).
// All staged indices provably in range: s0+22 <= 262, jW0+38 <= 262.
__global__ __launch_bounds__(256) void k_inv(const float* __restrict__ ll,
                                             const float* __restrict__ det,
                                             const float* __restrict__ tval,
                                             float* __restrict__ out) {
    __shared__ float sLL[23 * 40], sLH[23 * 40], sHL[23 * 40], sHH[23 * 40];
    __shared__ float sRL[32 * 40], sRH[32 * 40];
    const int m  = blockIdx.x;                   // channels adjacent in dispatch
    const int w0 = blockIdx.y * 64;              // 8 tiles
    const int t0 = blockIdx.z * 32;              // 16 tiles
    const int b = m / 3, c = m - 3 * (m / 3);
    const int tid = threadIdx.x;
    const float thr = tval[m];
    const int jW0 = w0 >> 1, s0 = t0 >> 1;
    const float* llp = ll + (size_t)m * DETPER;
    const float* dp  = det + (size_t)m * DETSTRIDE;
    for (int l = tid; l < 23 * 39; l += 256) {
        int rr = l / 39, cc = l - rr * 39;
        size_t o = (size_t)(s0 + rr) * NW_ + (jW0 + cc);
        int li = rr * 40 + cc;
        sLL[li] = llp[o];
        sLH[li] = softthr(dp[o], thr);
        sHL[li] = softthr(dp[DETPER + o], thr);
        sHH[li] = softthr(dp[2 * DETPER + o], thr);
    }
    __syncthreads();
    // column IDWT: rl/rh rows t0..t0+31 at 39 jW cols
    for (int l = tid; l < 32 * 39; l += 256) {
        int tr = l / 39, cc = l - tr * 39;
        int srow = tr >> 1, r = tr & 1;
        float aL = 0.f, aH = 0.f;
#pragma unroll
        for (int a = 0; a < 8; ++a) {
            int li = (srow + 7 - a) * 40 + cc;
            float wl = RLO[2 * a + r], wh = RHI[2 * a + r];
            aL = fmaf(sLL[li], wl, fmaf(sLH[li], wh, aL));
            aH = fmaf(sHL[li], wl, fmaf(sHH[li], wh, aH));
        }
        sRL[tr * 40 + cc] = aL;
        sRH[tr * 40 + cc] = aH;
    }
    __syncthreads();
    // row IDWT + NHWC store
    for (int l = tid; l < 32 * 64; l += 256) {
        int tr = l >> 6, wloc = l & 63;
        int r = wloc & 1, jb = (wloc >> 1) + 7;  // local col index base, in [7,38]
        float acc = 0.f;
#pragma unroll
        for (int a = 0; a < 8; ++a) {
            int li = tr * 40 + jb - a;
            acc = fmaf(sRL[li], RLO[2 * a + r], fmaf(sRH[li], RHI[2 * a + r], acc));
        }
        out[((size_t)(b * H_ + (t0 + tr)) * W_ + (w0 + wloc)) * C_ + c] = acc;
    }
}

extern "C" void kernel_launch(void* const* d_in, const int* in_sizes, int n_in,
                              void* d_out, int out_size, void* d_ws, size_t ws_size,
                              hipStream_t stream) {
    const float* x = (const float*)d_in[0];
    float* out = (float*)d_out;

    char* ws = (char*)d_ws;
    float* ll  = (float*)ws; ws += (size_t)M_ * DETPER * 4;     // 26.56 MB
    float* det = (float*)ws; ws += (size_t)M_ * DETSTRIDE * 4;  // 79.68 MB  [m][{lh,hl,hh}][DETPER]
    unsigned* hist1 = (unsigned*)ws; ws += (size_t)M_ * 2048 * 4;
    unsigned* hist2 = (unsigned*)ws; ws += (size_t)M_ * 2048 * 4;
    unsigned* hist3 = (unsigned*)ws; ws += (size_t)M_ * 1024 * 4;
    int*      selBin1 = (int*)ws;      ws += M_ * 4;
    int*      selBin2 = (int*)ws;      ws += M_ * 4;
    unsigned* rank1   = (unsigned*)ws; ws += M_ * 4;
    unsigned* rank2   = (unsigned*)ws; ws += M_ * 4;
    float*    tval    = (float*)ws;    ws += M_ * 4;
    // total ws usage: ~108.2 MB

    const int histWords = M_ * (2048 + 2048 + 1024);            // 491,520
    k_zero   <<<dim3((histWords + 255) / 256), 256, 0, stream>>>(hist1, histWords);
    k_fwd    <<<dim3(M_, 5, 17),  256, 0, stream>>>(x, ll, det);
    k_hist1  <<<dim3(M_, 16),     256, 0, stream>>>(det, hist1);
    k_sel2048<<<dim3(M_),         256, 0, stream>>>(hist1, nullptr, selBin1, rank1);
    k_hist2  <<<dim3(M_, 16),     256, 0, stream>>>(det, selBin1, hist2);
    k_sel2048<<<dim3(M_),         256, 0, stream>>>(hist2, rank1, selBin2, rank2);
    k_hist3  <<<dim3(M_, 16),     256, 0, stream>>>(det, selBin1, selBin2, hist3);
    k_sel3   <<<dim3(M_),         256, 0, stream>>>(hist3, rank2, selBin1, selBin2, tval);
    k_inv    <<<dim3(M_, 8, 16),  256, 0, stream>>>(ll, det, tval, out);
}